// Round 9
// baseline (167.423 us; speedup 1.0000x reference)
//
#include <hip/hip_runtime.h>

#define N_ 512
#define D_ 128
#define LOG2E 1.44269504088896f

// ws: xp_t bf16 TRANSPOSED [inst][f=128][s=512], 64 inst = 8,388,608 B.
// W-as-bf16 (128 KB) is staged in the FRONT OF d_out by wprep_kernel and
// consumed by proj_kernel; attn_kernel later overwrites all of d_out with h
// (stream-ordered), so no conflict and no extra ws needed.

typedef __attribute__((ext_vector_type(8))) short short8;
typedef __attribute__((ext_vector_type(4))) float floatx4;
typedef __attribute__((ext_vector_type(4))) unsigned int uintx4;

#if defined(__has_builtin)
#if __has_builtin(__builtin_amdgcn_exp2f)
#define EXP2F(x) __builtin_amdgcn_exp2f(x)
#else
#define EXP2F(x) exp2f(x)
#endif
#else
#define EXP2F(x) exp2f(x)
#endif

__device__ __forceinline__ unsigned short f2bf(float f) {
    unsigned int u = __float_as_uint(f);
    u += 0x7fffu + ((u >> 16) & 1u);
    return (unsigned short)(u >> 16);
}
__device__ __forceinline__ float bflo(unsigned int u) { return __uint_as_float(u << 16); }
__device__ __forceinline__ float bfhi(unsigned int u) { return __uint_as_float(u & 0xffff0000u); }
__device__ __forceinline__ float bf1(unsigned short s) { return __uint_as_float(((unsigned int)s) << 16); }

// ---------------------------------------------------------------------------
// Kernel 0: W fp32 -> bf16 (RNE), 65536 values into d_out[0:128KB].
// ---------------------------------------------------------------------------
__global__ __launch_bounds__(256) void wprep_kernel(
    const float* __restrict__ W, unsigned short* __restrict__ wbf)
{
    const int idx = (blockIdx.x * 256 + threadIdx.x) * 4;
    const float4 v = *(const float4*)&W[idx];
    uint2 pk;
    pk.x = f2bf(v.x) | ((unsigned int)f2bf(v.y) << 16);
    pk.y = f2bf(v.z) | ((unsigned int)f2bf(v.w) << 16);
    *(uint2*)&wbf[idx] = pk;
}

// ---------------------------------------------------------------------------
// Kernel 1: proj via MFMA, NO LDS / NO barriers. Block = (64-row ntile, inst),
// 4 waves; wave owns 16 rows x 128 f. A-frags built in-lane from fp32 x;
// B-frags are direct 16 B global loads of bf16 W (L2-hot, slab shared by 8
// blocks). xp_t[inst][f][n] = sum_c x*W + pb, bf16 transposed.
// C/D: col=lane&15 (f), row=q*4+reg (n row) [m89-verified].
// ---------------------------------------------------------------------------
__global__ __launch_bounds__(256) void proj_kernel(
    const float* __restrict__ x,
    const unsigned short* __restrict__ wbf,
    const float* __restrict__ pb,
    unsigned short* __restrict__ xpt)
{
    const int ntile = blockIdx.x;   // 0..7
    const int inst  = blockIdx.y;   // 0..63
    const int j = inst & 1;
    const int bi = inst >> 1;
    const int ij = (bi & 1) * 2 + j;
    const int t = threadIdx.x;
    const int wave = t >> 6, L = t & 63, n = L & 15, q = L >> 4;

    const int n0w = ntile * 64 + wave * 16;
    const float* xrow = x + ((size_t)bi * N_ + n0w + n) * D_ + q * 8;
    short8 Af[4];
#pragma unroll
    for (int kc = 0; kc < 4; ++kc) {
        const float4 a0 = *(const float4*)(xrow + kc * 32);
        const float4 a1 = *(const float4*)(xrow + kc * 32 + 4);
        uintx4 au;
        au.x = f2bf(a0.x) | ((unsigned int)f2bf(a0.y) << 16);
        au.y = f2bf(a0.z) | ((unsigned int)f2bf(a0.w) << 16);
        au.z = f2bf(a1.x) | ((unsigned int)f2bf(a1.y) << 16);
        au.w = f2bf(a1.z) | ((unsigned int)f2bf(a1.w) << 16);
        Af[kc] = __builtin_bit_cast(short8, au);
    }

    const unsigned short* wb = wbf + (size_t)ij * D_ * D_;
#pragma unroll
    for (int ft = 0; ft < 8; ++ft) {
        floatx4 C = (floatx4){0.f, 0.f, 0.f, 0.f};
#pragma unroll
        for (int kc = 0; kc < 4; ++kc) {
            const short8 Bf = *(const short8*)(wb + (size_t)(ft * 16 + n) * D_ + kc * 32 + q * 8);
            C = __builtin_amdgcn_mfma_f32_16x16x32_bf16(Af[kc], Bf, C, 0, 0, 0);
        }
        const int fg = ft * 16 + n;
        const float pbv = pb[ij * D_ + fg];
        uint2 pk;
        pk.x = f2bf(C[0] + pbv) | ((unsigned int)f2bf(C[1] + pbv) << 16);
        pk.y = f2bf(C[2] + pbv) | ((unsigned int)f2bf(C[3] + pbv) << 16);
        *(uint2*)&xpt[((size_t)inst * D_ + fg) * N_ + n0w + q * 4] = pk;
    }
}

// ---------------------------------------------------------------------------
// Kernel 2: attention via MFMA (unchanged from R8). Block = (bi, 16-dst
// tile); 4 waves, wave owns 2 heads. w A-fragments built in-lane (8 exp2 per
// MFMA) against B = xp_t rows. Scores in log2 domain; w truncated to bf16 so
// Z and the numerator match. No barriers in the K-loop.
// ---------------------------------------------------------------------------
__global__ __launch_bounds__(256) void attn_kernel(
    const unsigned short* __restrict__ xpt,
    const int* __restrict__ A,
    const float* __restrict__ att_src,
    const float* __restrict__ att_dst,
    const float* __restrict__ bias,
    float* __restrict__ hout)
{
    __shared__ float ss_t[8][N_];
    __shared__ unsigned int mask_l[2][N_];
    __shared__ float sd_l[8][16];
    __shared__ float z_l[8][16];
    __shared__ float as_l[128];
    __shared__ float ad_l[128];

    const int tile = blockIdx.x;   // 0..31
    const int bi   = blockIdx.y;   // 0..31
    const int i_ = bi & 1;
    const int d0 = tile * 16;
    const int t = threadIdx.x;
    const int wave = t >> 6, L = t & 63, n = L & 15, q = L >> 4;
    const int h0 = wave * 2;

#pragma unroll
    for (int rep = 0; rep < 2; ++rep) {
        const int s = t + rep * 256;
        const int* Ar = A + ((size_t)bi * N_ + s) * N_ + d0;
        unsigned int m0 = 0, m1 = 0;
#pragma unroll
        for (int g = 0; g < 4; ++g) {
            const int4 v = *(const int4*)(Ar + g * 4);
            const int k = g * 4;
            if (v.x == 2 || v.x == 4) m0 |= 1u << (k + 0);
            if (v.x == 3 || v.x == 4) m1 |= 1u << (k + 0);
            if (v.y == 2 || v.y == 4) m0 |= 1u << (k + 1);
            if (v.y == 3 || v.y == 4) m1 |= 1u << (k + 1);
            if (v.z == 2 || v.z == 4) m0 |= 1u << (k + 2);
            if (v.z == 3 || v.z == 4) m1 |= 1u << (k + 2);
            if (v.w == 2 || v.w == 4) m0 |= 1u << (k + 3);
            if (v.w == 3 || v.w == 4) m1 |= 1u << (k + 3);
        }
        mask_l[0][s] = m0;
        mask_l[1][s] = m1;
    }

    float hacc[2][4];
#pragma unroll
    for (int a = 0; a < 2; ++a)
#pragma unroll
        for (int b = 0; b < 4; ++b) hacc[a][b] = 0.f;

    for (int j = 0; j < 2; ++j) {
        const int inst = bi * 2 + j;
        const int ij = i_ * 2 + j;
        const unsigned short* xpi = xpt + (size_t)inst * D_ * N_;

        __syncthreads();
        if (t < 128) {
            as_l[t] = att_src[ij * D_ + t] * LOG2E;
            ad_l[t] = att_dst[ij * D_ + t] * LOG2E;
        }
        __syncthreads();

        {
            const int hh = t >> 5;
            const int sb = (t & 31) * 16;
            float accs[16];
#pragma unroll
            for (int k = 0; k < 16; ++k) accs[k] = 0.f;
#pragma unroll 4
            for (int f = 0; f < 16; ++f) {
                const unsigned short* row = xpi + (size_t)(hh * 16 + f) * N_ + sb;
                const uint4 a0 = *(const uint4*)row;
                const uint4 a1 = *(const uint4*)(row + 8);
                const float av = as_l[hh * 16 + f];
                accs[0]  += bflo(a0.x) * av; accs[1]  += bfhi(a0.x) * av;
                accs[2]  += bflo(a0.y) * av; accs[3]  += bfhi(a0.y) * av;
                accs[4]  += bflo(a0.z) * av; accs[5]  += bfhi(a0.z) * av;
                accs[6]  += bflo(a0.w) * av; accs[7]  += bfhi(a0.w) * av;
                accs[8]  += bflo(a1.x) * av; accs[9]  += bfhi(a1.x) * av;
                accs[10] += bflo(a1.y) * av; accs[11] += bfhi(a1.y) * av;
                accs[12] += bflo(a1.z) * av; accs[13] += bfhi(a1.z) * av;
                accs[14] += bflo(a1.w) * av; accs[15] += bfhi(a1.w) * av;
            }
#pragma unroll
            for (int k = 0; k < 16; ++k) ss_t[hh][sb + k] = accs[k];
        }
        if (t < 128) {
            const int dd = t >> 3;
            const int hh = t & 7;
            float s = 0.f;
#pragma unroll
            for (int f = 0; f < 16; ++f)
                s += bf1(xpi[(size_t)(hh * 16 + f) * N_ + d0 + dd]) * ad_l[hh * 16 + f];
            sd_l[hh][dd] = s;
        }
        __syncthreads();

        const float sdv[2] = { sd_l[h0][n], sd_l[h0 + 1][n] };

        floatx4 Cacc[2] = { (floatx4){0.f,0.f,0.f,0.f}, (floatx4){0.f,0.f,0.f,0.f} };
        float zacc[2] = { 0.f, 0.f };

        for (int c = 0; c < 16; ++c) {
            const int sq = c * 32 + q * 8;
            short8 Bf[2];
            Bf[0] = *(const short8*)(xpi + (size_t)(h0 * 16 + n) * N_ + sq);
            Bf[1] = *(const short8*)(xpi + (size_t)((h0 + 1) * 16 + n) * N_ + sq);
            const uint4 m0v = *(const uint4*)&mask_l[j][sq];
            const uint4 m1v = *(const uint4*)&mask_l[j][sq + 4];
            const unsigned int mw[8] = { m0v.x, m0v.y, m0v.z, m0v.w,
                                         m1v.x, m1v.y, m1v.z, m1v.w };
#pragma unroll
            for (int hh2 = 0; hh2 < 2; ++hh2) {
                const float4 s0v = *(const float4*)&ss_t[h0 + hh2][sq];
                const float4 s1v = *(const float4*)&ss_t[h0 + hh2][sq + 4];
                const float ssv[8] = { s0v.x, s0v.y, s0v.z, s0v.w,
                                       s1v.x, s1v.y, s1v.z, s1v.w };
                unsigned int wt[8];
#pragma unroll
                for (int idx = 0; idx < 8; ++idx) {
                    const float z0 = ssv[idx] + sdv[hh2];
                    const float zr = fmaxf(z0, 0.2f * z0);
                    const float e = EXP2F(zr);
                    const float w = ((mw[idx] >> n) & 1u) ? e : 1.0f;
                    wt[idx] = __float_as_uint(w) & 0xffff0000u;
                    zacc[hh2] += __uint_as_float(wt[idx]);
                }
                uintx4 au;
                au.x = __builtin_amdgcn_perm(wt[1], wt[0], 0x07060302);
                au.y = __builtin_amdgcn_perm(wt[3], wt[2], 0x07060302);
                au.z = __builtin_amdgcn_perm(wt[5], wt[4], 0x07060302);
                au.w = __builtin_amdgcn_perm(wt[7], wt[6], 0x07060302);
                Cacc[hh2] = __builtin_amdgcn_mfma_f32_16x16x32_bf16(
                    __builtin_bit_cast(short8, au), Bf[hh2], Cacc[hh2], 0, 0, 0);
            }
        }

#pragma unroll
        for (int hh2 = 0; hh2 < 2; ++hh2) {
            float z = zacc[hh2];
            z += __shfl_xor(z, 16);
            z += __shfl_xor(z, 32);
            zacc[hh2] = z;
        }
        if (q == 0) { z_l[h0][n] = zacc[0]; z_l[h0 + 1][n] = zacc[1]; }

#pragma unroll
        for (int hh2 = 0; hh2 < 2; ++hh2) {
            const int h = h0 + hh2;
            const float bv = bias[ij * D_ + h * 16 + n];
            const uint2 sv = *(const uint2*)(xpi + (size_t)(h * 16 + n) * N_ + d0 + q * 4);
            const float selfv[4] = { bflo(sv.x), bfhi(sv.x), bflo(sv.y), bfhi(sv.y) };
#pragma unroll
            for (int reg = 0; reg < 4; ++reg) {
                const float Zi = 1.0f / z_l[h][q * 4 + reg];
                hacc[hh2][reg] += Cacc[hh2][reg] * Zi + selfv[reg] + bv;
            }
        }
    }

#pragma unroll
    for (int hh2 = 0; hh2 < 2; ++hh2)
#pragma unroll
        for (int reg = 0; reg < 4; ++reg)
            hout[((size_t)bi * N_ + d0 + q * 4 + reg) * D_ + (h0 + hh2) * 16 + n]
                = hacc[hh2][reg];
}

// ---------------------------------------------------------------------------
// Kernel 3: in-place mix on d_out (thread owns both i slices of one b).
// ---------------------------------------------------------------------------
__global__ __launch_bounds__(256) void combine_kernel(float* __restrict__ h)
{
    const int idx = blockIdx.x * 256 + threadIdx.x;
    const int b = idx >> 14;
    const int r = idx & 16383;
    float4* p0 = (float4*)h + (size_t)b * 32768 + r;
    float4* p1 = p0 + 16384;
    const float4 a = *p0;
    const float4 o = *p1;
    float4 r0, r1;
    r0.x = 1.5f * a.x + 0.5f * o.x;  r1.x = 1.5f * o.x + 0.5f * a.x;
    r0.y = 1.5f * a.y + 0.5f * o.y;  r1.y = 1.5f * o.y + 0.5f * a.y;
    r0.z = 1.5f * a.z + 0.5f * o.z;  r1.z = 1.5f * o.z + 0.5f * a.z;
    r0.w = 1.5f * a.w + 0.5f * o.w;  r1.w = 1.5f * o.w + 0.5f * a.w;
    *p0 = r0;
    *p1 = r1;
}

extern "C" void kernel_launch(void* const* d_in, const int* in_sizes, int n_in,
                              void* d_out, int out_size, void* d_ws, size_t ws_size,
                              hipStream_t stream)
{
    const float* x   = (const float*)d_in[0];
    const int*   A   = (const int*)d_in[1];
    const float* W   = (const float*)d_in[2];
    const float* pb  = (const float*)d_in[3];
    const float* as_ = (const float*)d_in[4];
    const float* ad_ = (const float*)d_in[5];
    const float* bs  = (const float*)d_in[6];

    unsigned short* xpt = (unsigned short*)d_ws;   // 8,388,608 B
    unsigned short* wbf = (unsigned short*)d_out;  // 128 KB scratch, then h
    float* h = (float*)d_out;

    wprep_kernel<<<64, 256, 0, stream>>>(W, wbf);
    proj_kernel<<<dim3(8, 64), 256, 0, stream>>>(x, wbf, pb, xpt);
    attn_kernel<<<dim3(32, 32), 256, 0, stream>>>(xpt, A, as_, ad_, bs, h);
    combine_kernel<<<1024, 256, 0, stream>>>(h);
}